// Round 1
// baseline (20.630 us; speedup 1.0000x reference)
//
#include <hip/hip_runtime.h>
#include <math.h>

#define BB 8
#define NN 64
#define TT 128
#define TM1 127
#define NIN 8

__device__ __forceinline__ float lrelu(float v) { return v > 0.0f ? v : 0.01f * v; }

__global__ __launch_bounds__(256) void gat_kernel(
    const float* __restrict__ x,       // (8,64,128,8)
    const float* __restrict__ W_sp,    // (24,64)
    const float* __restrict__ b_sp,    // (64)
    const float* __restrict__ W_node,  // (8,64)
    const float* __restrict__ b_node,  // (64)
    const float* __restrict__ W_att,   // (64,1)
    const float* __restrict__ b_att,   // (1)
    float* __restrict__ out)           // (8,127,64,64)
{
    const int bt = blockIdx.x;
    const int b = bt / TM1;
    const int t = bt - b * TM1;
    const int tid = threadIdx.x;
    const int lane = tid & 63;
    const int wid = tid >> 6;

    // ne[f][d], padded to 68 floats (272B, 16B-aligned rows, conflict-free)
    __shared__ __align__(16) float ne[64][68];
    // ST shares space with the x staging tiles (x dead before ST is written)
    __shared__ __align__(16) float stbuf[64 * 68];
    float (*x2)[64][9] = (float (*)[64][9])stbuf;   // [2][64][9] = 1152 floats
    float (*ST)[68] = (float (*)[68])stbuf;          // ST[f][n] = S[n][f]
    __shared__ float u_sh[64], w_sh[64];
    __shared__ float pvec[8], qvec[8];
    __shared__ float cc[2]; // c0 (b_sp.Watt), c1 (b_node.Watt)
    __shared__ float redmax[4][64], redsum[4][64];

    // ---- phase 0: stage x_t, x_{t+1}; reduce p,q,c0,c1 on wave 0 ----
    {
        int n = tid >> 2;
        int sel = tid & 3;
        int tile = sel >> 1, half = sel & 1;
        const float* src = x + (((b * NN + n) * TT) + (t + tile)) * NIN + half * 4;
        float4 v = *(const float4*)src;
        float* dst = &x2[tile][n][half * 4];
        dst[0] = v.x; dst[1] = v.y; dst[2] = v.z; dst[3] = v.w;
    }
    float Wn[8];
#pragma unroll
    for (int k = 0; k < 8; ++k) Wn[k] = W_node[k * 64 + lane];
    const float bnode_d = b_node[lane];
    const float batt = b_att[0];

    if (wid == 0) {
        float wa = W_att[lane];
        float vals[18];
#pragma unroll
        for (int k = 0; k < 8; ++k) vals[k] = W_node[k * 64 + lane] * wa;
#pragma unroll
        for (int k = 0; k < 8; ++k)
            vals[8 + k] = (W_sp[(8 + k) * 64 + lane] + W_sp[(16 + k) * 64 + lane]) * wa;
        vals[16] = b_sp[lane] * wa;
        vals[17] = b_node[lane] * wa;
#pragma unroll
        for (int i = 0; i < 18; ++i) {
            float v = vals[i];
#pragma unroll
            for (int off = 32; off > 0; off >>= 1) v += __shfl_xor(v, off, 64);
            vals[i] = v;
        }
        if (lane == 0) {
#pragma unroll
            for (int k = 0; k < 8; ++k) { pvec[k] = vals[k]; qvec[k] = vals[8 + k]; }
            cc[0] = vals[16]; cc[1] = vals[17];
        }
    }
    __syncthreads();

    // ---- phase 1: u[n], w[n] (wave part) + ne[f][d] (all threads) ----
    if (tid < 64) {
        float su = 0.f, sw = 0.f;
#pragma unroll
        for (int k = 0; k < 8; ++k) {
            float a0 = x2[0][tid][k];
            float a1 = x2[1][tid][k];
            su += a0 * pvec[k];
            sw += (a1 - a0) * qvec[k];
        }
        u_sh[tid] = su + cc[1];
        w_sh[tid] = sw + cc[0];
    }
#pragma unroll
    for (int it = 0; it < 16; ++it) {
        int f = wid * 16 + it;
        float acc = bnode_d;
#pragma unroll
        for (int k = 0; k < 8; ++k) acc += x2[0][f][k] * Wn[k];
        ne[f][lane] = acc;
    }
    __syncthreads();  // x2 dead from here; u,w,ne ready

    // ---- phase 2: ST[f][n] = S[n][f] = lrelu(u[n]+u[f]+w[f]+b_att), 0 on diag ----
    {
        const float ul = u_sh[lane];
#pragma unroll
        for (int it = 0; it < 16; ++it) {
            int f = wid * 16 + it;
            float c = u_sh[f] + w_sh[f] + batt;
            float v = lrelu(ul + c);
            ST[f][lane] = (f == lane) ? 0.0f : v;
        }
    }
    __syncthreads();

    // ---- phase 3: softmax over f (columns of ST), 4 threads per column ----
    {
        const int n = lane, q = wid;
        float pm = -1e30f;
#pragma unroll
        for (int j = 0; j < 16; ++j) pm = fmaxf(pm, ST[q * 16 + j][n]);
        redmax[q][n] = pm;
        __syncthreads();
        float m = fmaxf(fmaxf(redmax[0][n], redmax[1][n]),
                        fmaxf(redmax[2][n], redmax[3][n]));
        float ps = 0.f;
#pragma unroll
        for (int j = 0; j < 16; ++j) {
            int f = q * 16 + j;
            float e = __expf(ST[f][n] - m);
            ST[f][n] = e;
            ps += e;
        }
        redsum[q][n] = ps;
        __syncthreads();
        float inv = 1.0f / (redsum[0][n] + redsum[1][n] + redsum[2][n] + redsum[3][n]);
#pragma unroll
        for (int j = 0; j < 16; ++j) ST[q * 16 + j][n] *= inv;
    }
    __syncthreads();

    // ---- phase 4: out[n][d] = lrelu(sum_f S[n][f]*ne[f][d]); 4x4 register tile ----
    {
        const int r = tid >> 4;   // rows 4r..4r+3
        const int c = tid & 15;   // cols 4c..4c+3
        float acc[4][4];
#pragma unroll
        for (int i = 0; i < 4; ++i)
#pragma unroll
            for (int j = 0; j < 4; ++j) acc[i][j] = 0.f;

#pragma unroll 4
        for (int f = 0; f < 64; ++f) {
            float4 sv = *(const float4*)&ST[f][4 * r];  // S[4r+i][f]
            float4 nv = *(const float4*)&ne[f][4 * c];
            acc[0][0] += sv.x * nv.x; acc[0][1] += sv.x * nv.y; acc[0][2] += sv.x * nv.z; acc[0][3] += sv.x * nv.w;
            acc[1][0] += sv.y * nv.x; acc[1][1] += sv.y * nv.y; acc[1][2] += sv.y * nv.z; acc[1][3] += sv.y * nv.w;
            acc[2][0] += sv.z * nv.x; acc[2][1] += sv.z * nv.y; acc[2][2] += sv.z * nv.z; acc[2][3] += sv.z * nv.w;
            acc[3][0] += sv.w * nv.x; acc[3][1] += sv.w * nv.y; acc[3][2] += sv.w * nv.z; acc[3][3] += sv.w * nv.w;
        }
        const long base0 = ((long)(b * TM1 + t)) * 64 * 64;
#pragma unroll
        for (int i = 0; i < 4; ++i) {
            float4 o;
            o.x = lrelu(acc[i][0]);
            o.y = lrelu(acc[i][1]);
            o.z = lrelu(acc[i][2]);
            o.w = lrelu(acc[i][3]);
            *(float4*)(out + base0 + (long)(4 * r + i) * 64 + 4 * c) = o;
        }
    }
}

extern "C" void kernel_launch(void* const* d_in, const int* in_sizes, int n_in,
                              void* d_out, int out_size, void* d_ws, size_t ws_size,
                              hipStream_t stream) {
    const float* x      = (const float*)d_in[0];
    // d_in[1]=rel_rec, d_in[2]=rel_send: one-hot edge matrices, index math instead
    const float* W_sp   = (const float*)d_in[3];
    const float* b_sp   = (const float*)d_in[4];
    const float* W_node = (const float*)d_in[5];
    const float* b_node = (const float*)d_in[6];
    const float* W_att  = (const float*)d_in[7];
    const float* b_att  = (const float*)d_in[8];
    float* out = (float*)d_out;

    dim3 grid(BB * TM1);
    dim3 block(256);
    hipLaunchKernelGGL(gat_kernel, grid, block, 0, stream,
                       x, W_sp, b_sp, W_node, b_node, W_att, b_att, out);
}

// Round 2
// 16.400 us; speedup vs baseline: 1.2579x; 1.2579x over previous
//
#include <hip/hip_runtime.h>
#include <math.h>

#define BB 8
#define TM1 127

typedef _Float16 f16x4 __attribute__((ext_vector_type(4)));
typedef float f32x4 __attribute__((ext_vector_type(4)));
typedef unsigned int u32x4 __attribute__((ext_vector_type(4)));

__device__ __forceinline__ float lrelu(float v) { return v > 0.0f ? v : 0.01f * v; }

__global__ __launch_bounds__(256, 4) void gat_kernel(
    const float* __restrict__ x,       // (8,64,128,8)
    const float* __restrict__ W_sp,    // (24,64)
    const float* __restrict__ b_sp,    // (64)
    const float* __restrict__ W_node,  // (8,64)
    const float* __restrict__ b_node,  // (64)
    const float* __restrict__ W_att,   // (64,1)
    const float* __restrict__ b_att,   // (1)
    float* __restrict__ out)           // (8,127,64,64)
{
    const int bt = blockIdx.x;
    const int b = bt / TM1;
    const int t = bt - b * TM1;
    const int tid = threadIdx.x;
    const int lane = tid & 63;
    const int wid = tid >> 6;

    __shared__ __align__(16) float x2[2][64][8];            // 4 KB
    __shared__ __align__(16) unsigned short Nh[64][72];     // 9 KB  (f16 hi, [d][f], 144B rows)
    __shared__ __align__(16) unsigned short Nl[64][72];     // 9 KB  (f16 lo)
    __shared__ __align__(16) float u_sh[64], w_sh[64];
    __shared__ float pvec[8], qvec[8], cc[2];

    // ---- phase 0: stage x_t, x_{t+1}; wave 0 reduces p,q,c0,c1 ----
    {
        int n = tid >> 2;
        int sel = tid & 3;
        int tile = sel >> 1, half = sel & 1;
        const float* src = x + (((long)(b * 64 + n) * 128) + (t + tile)) * 8 + half * 4;
        *(float4*)&x2[tile][n][half * 4] = *(const float4*)src;
    }
    float Wn[8];
#pragma unroll
    for (int k = 0; k < 8; ++k) Wn[k] = W_node[k * 64 + lane];
    const float bnode_d = b_node[lane];
    const float batt = b_att[0];

    if (wid == 0) {
        float wa = W_att[lane];
        float vals[18];
#pragma unroll
        for (int k = 0; k < 8; ++k) vals[k] = W_node[k * 64 + lane] * wa;
#pragma unroll
        for (int k = 0; k < 8; ++k)
            vals[8 + k] = (W_sp[(8 + k) * 64 + lane] + W_sp[(16 + k) * 64 + lane]) * wa;
        vals[16] = b_sp[lane] * wa;
        vals[17] = b_node[lane] * wa;
#pragma unroll
        for (int i = 0; i < 18; ++i) {
            float v = vals[i];
#pragma unroll
            for (int off = 32; off > 0; off >>= 1) v += __shfl_xor(v, off, 64);
            vals[i] = v;
        }
        if (lane == 0) {
#pragma unroll
            for (int k = 0; k < 8; ++k) { pvec[k] = vals[k]; qvec[k] = vals[8 + k]; }
            cc[0] = vals[16]; cc[1] = vals[17];
        }
    }
    __syncthreads();

    // ---- phase 1a: u[n], w[n] ----
    if (tid < 64) {
        f32x4 a0 = *(const f32x4*)&x2[0][tid][0];
        f32x4 a1 = *(const f32x4*)&x2[0][tid][4];
        f32x4 c0 = *(const f32x4*)&x2[1][tid][0];
        f32x4 c1 = *(const f32x4*)&x2[1][tid][4];
        float su = 0.f, sw = 0.f;
#pragma unroll
        for (int e = 0; e < 4; ++e) {
            su += a0[e] * pvec[e] + a1[e] * pvec[4 + e];
            sw += (c0[e] - a0[e]) * qvec[e] + (c1[e] - a1[e]) * qvec[4 + e];
        }
        u_sh[tid] = su + cc[1];
        w_sh[tid] = sw + cc[0];
    }

    // ---- phase 1b: ne[f][d] = x_t@W_node + b ; split f16 hi/lo, write [d][f] ----
    {
        float av[16];
#pragma unroll
        for (int it = 0; it < 16; ++it) {
            int f = wid * 16 + it;
            f32x4 xa = *(const f32x4*)&x2[0][f][0];
            f32x4 xb = *(const f32x4*)&x2[0][f][4];
            float acc = bnode_d;
            acc += xa[0] * Wn[0] + xa[1] * Wn[1] + xa[2] * Wn[2] + xa[3] * Wn[3];
            acc += xb[0] * Wn[4] + xb[1] * Wn[5] + xb[2] * Wn[6] + xb[3] * Wn[7];
            av[it] = acc;
        }
        unsigned int hw[8], lw[8];
#pragma unroll
        for (int p = 0; p < 8; ++p) {
            float v0 = av[2 * p], v1 = av[2 * p + 1];
            _Float16 h0 = (_Float16)v0, h1 = (_Float16)v1;
            _Float16 l0 = (_Float16)(v0 - (float)h0);
            _Float16 l1 = (_Float16)(v1 - (float)h1);
            hw[p] = (unsigned int)__builtin_bit_cast(unsigned short, h0) |
                    ((unsigned int)__builtin_bit_cast(unsigned short, h1) << 16);
            lw[p] = (unsigned int)__builtin_bit_cast(unsigned short, l0) |
                    ((unsigned int)__builtin_bit_cast(unsigned short, l1) << 16);
        }
        u32x4 qa = {hw[0], hw[1], hw[2], hw[3]};
        u32x4 qb = {hw[4], hw[5], hw[6], hw[7]};
        u32x4 qc = {lw[0], lw[1], lw[2], lw[3]};
        u32x4 qd = {lw[4], lw[5], lw[6], lw[7]};
        *(u32x4*)&Nh[lane][wid * 16]     = qa;
        *(u32x4*)&Nh[lane][wid * 16 + 8] = qb;
        *(u32x4*)&Nl[lane][wid * 16]     = qc;
        *(u32x4*)&Nl[lane][wid * 16 + 8] = qd;
    }
    __syncthreads();

    // ---- phase 2: S + softmax in registers (A-frag layout), MFMA, store ----
    {
        const int i = lane & 15;
        const int g = lane >> 4;
        const int g4 = g * 4;
        const int n = wid * 16 + i;          // this lane's attention row
        const float un = u_sh[n];

        float a[16];
#pragma unroll
        for (int s4 = 0; s4 < 4; ++s4) {
            f32x4 uf = *(const f32x4*)&u_sh[s4 * 16 + g4];
            f32x4 wf = *(const f32x4*)&w_sh[s4 * 16 + g4];
#pragma unroll
            for (int e = 0; e < 4; ++e) {
                int f = s4 * 16 + g4 + e;
                float v = lrelu(un + uf[e] + wf[e] + batt);
                a[s4 * 4 + e] = (f == n) ? 0.0f : v;
            }
        }
        // row softmax: row n lives in lanes {i, i+16, i+32, i+48}
        float m = a[0];
#pragma unroll
        for (int j = 1; j < 16; ++j) m = fmaxf(m, a[j]);
        m = fmaxf(m, __shfl_xor(m, 16, 64));
        m = fmaxf(m, __shfl_xor(m, 32, 64));
        float s = 0.f;
#pragma unroll
        for (int j = 0; j < 16; ++j) {
            float e = __expf(a[j] - m);
            a[j] = e;
            s += e;
        }
        s += __shfl_xor(s, 16, 64);
        s += __shfl_xor(s, 32, 64);
        const float inv = 1.0f / s;

        f16x4 Ah[4], Al[4];
#pragma unroll
        for (int s4 = 0; s4 < 4; ++s4) {
#pragma unroll
            for (int e = 0; e < 4; ++e) {
                float v = a[s4 * 4 + e] * inv;
                _Float16 h = (_Float16)v;
                Ah[s4][e] = h;
                Al[s4][e] = (_Float16)(v - (float)h);
            }
        }

        f32x4 acc[4];
#pragma unroll
        for (int c = 0; c < 4; ++c) acc[c] = (f32x4){0.f, 0.f, 0.f, 0.f};

#pragma unroll
        for (int c = 0; c < 4; ++c) {
            const int col = c * 16 + i;
#pragma unroll
            for (int s4 = 0; s4 < 4; ++s4) {
                f16x4 bh = *(const f16x4*)&Nh[col][s4 * 16 + g4];
                f16x4 bl = *(const f16x4*)&Nl[col][s4 * 16 + g4];
                acc[c] = __builtin_amdgcn_mfma_f32_16x16x16f16(Ah[s4], bh, acc[c], 0, 0, 0);
                acc[c] = __builtin_amdgcn_mfma_f32_16x16x16f16(Al[s4], bh, acc[c], 0, 0, 0);
                acc[c] = __builtin_amdgcn_mfma_f32_16x16x16f16(Ah[s4], bl, acc[c], 0, 0, 0);
            }
        }

        float* op = out + ((long)(b * TM1 + t) << 12);
#pragma unroll
        for (int c = 0; c < 4; ++c) {
#pragma unroll
            for (int r = 0; r < 4; ++r) {
                int row = wid * 16 + g4 + r;     // C/D: row = 4*(lane>>4)+reg
                op[row * 64 + c * 16 + i] = lrelu(acc[c][r]);
            }
        }
    }
}

extern "C" void kernel_launch(void* const* d_in, const int* in_sizes, int n_in,
                              void* d_out, int out_size, void* d_ws, size_t ws_size,
                              hipStream_t stream) {
    const float* x      = (const float*)d_in[0];
    // d_in[1]=rel_rec, d_in[2]=rel_send: one-hot edge matrices, replaced by index math
    const float* W_sp   = (const float*)d_in[3];
    const float* b_sp   = (const float*)d_in[4];
    const float* W_node = (const float*)d_in[5];
    const float* b_node = (const float*)d_in[6];
    const float* W_att  = (const float*)d_in[7];
    const float* b_att  = (const float*)d_in[8];
    float* out = (float*)d_out;

    dim3 grid(BB * TM1);
    dim3 block(256);
    hipLaunchKernelGGL(gat_kernel, grid, block, 0, stream,
                       x, W_sp, b_sp, W_node, b_node, W_att, b_att, out);
}